// Round 5
// baseline (1424.065 us; speedup 1.0000x reference)
//
#include <hip/hip_runtime.h>
#include <stdint.h>

#define T_SEQ 128
#define B_SZ  32
#define H_DIM 1024
#define E_DIM 512
#define V_DIM 32000
#define SOS_TOK 1

typedef float v4f __attribute__((ext_vector_type(4)));
typedef short short8 __attribute__((ext_vector_type(8)));

// RNE float->bf16
__device__ inline uint16_t f2bf(float x) {
    uint32_t u = __float_as_uint(x);
    uint32_t r = (u + 0x7fffu + ((u >> 16) & 1u)) >> 16;
    return (uint16_t)r;
}
__device__ inline uint32_t pack2(float a, float b) {
    return (uint32_t)f2bf(a) | ((uint32_t)f2bf(b) << 16);
}

// inline tanh: no ocml libcall. Exact at 0/+inf/-inf, err ~1e-6.
__device__ inline float fast_tanh(float x) {
    float e = __expf(2.0f * x);
    return 1.0f - __fdividef(2.0f, e + 1.0f);
}

// async global->LDS, 16B per lane. lds base must be wave-uniform.
__device__ inline void gload16(const void* g, void* l) {
    __builtin_amdgcn_global_load_lds(
        (const __attribute__((address_space(1))) uint32_t*)g,
        (__attribute__((address_space(3))) uint32_t*)l, 16, 0, 0);
}

// ---------------------------------------------------------------------------
// kconv: fp32 -> bf16, 2048 elements per block
// ---------------------------------------------------------------------------
__global__ __launch_bounds__(256) void kconv(const float* __restrict__ W,
                                             uint16_t* __restrict__ Wb) {
    size_t i = ((size_t)blockIdx.x * 256 + threadIdx.x) * 8;
    float4 a = *(const float4*)&W[i];
    float4 c = *(const float4*)&W[i + 4];
    uint4 p;
    p.x = pack2(a.x, a.y); p.y = pack2(a.z, a.w);
    p.z = pack2(c.x, c.y); p.w = pack2(c.z, c.w);
    *(uint4*)&Wb[i] = p;
}

// ---------------------------------------------------------------------------
// kxwm: xW[m][n] = emb[tok(m)] . Wih[n] + bih[n] + bhh[n]   (bf16 MFMA)
// M=4096, N=1024, K=512. 128x128 tile, BK=32, 4 waves. fp32->bf16 reg-staged
// (same staging/epilogue pattern as the R1-validated kgemm<false>).
// grid (32, 8).
// ---------------------------------------------------------------------------
__global__ __launch_bounds__(256) void kxwm(const int* __restrict__ target,
                                            const float* __restrict__ emb,
                                            const float* __restrict__ Wih,
                                            const float* __restrict__ bih,
                                            const float* __restrict__ bhh,
                                            float* __restrict__ xW) {
    __shared__ __align__(16) uint16_t As[128 * 32];
    __shared__ __align__(16) uint16_t Bs[128 * 32];
    __shared__ int toks[128];
    int m0 = blockIdx.x * 128, n0 = blockIdx.y * 128;
    int tid = threadIdx.x;
    if (tid < 128) {
        int row = m0 + tid;
        int t = row & (T_SEQ - 1);
        toks[tid] = (t == 0) ? SOS_TOK : target[row];
    }
    __syncthreads();

    v4f acc[4][4] = {};
    int lane = tid & 63, wv = tid >> 6, wm = wv >> 1, wn = wv & 1;
    int ar = lane & 15, ko = (lane >> 4) * 8;

    for (int k0 = 0; k0 < E_DIM; k0 += 32) {
#pragma unroll
        for (int l = 0; l < 2; ++l) {
            int c = tid + l * 256;
            int r = c >> 2, ko8 = (c & 3) * 8;
            const float* asrc = &emb[(size_t)toks[r] * E_DIM + k0 + ko8];
            float4 x = *(const float4*)asrc;
            float4 y = *(const float4*)(asrc + 4);
            uint4 p;
            p.x = pack2(x.x, x.y); p.y = pack2(x.z, x.w);
            p.z = pack2(y.x, y.y); p.w = pack2(y.z, y.w);
            *(uint4*)&As[r * 32 + ko8] = p;
            const float* bsrc = &Wih[(size_t)(n0 + r) * E_DIM + k0 + ko8];
            float4 u = *(const float4*)bsrc;
            float4 v = *(const float4*)(bsrc + 4);
            uint4 q;
            q.x = pack2(u.x, u.y); q.y = pack2(u.z, u.w);
            q.z = pack2(v.x, v.y); q.w = pack2(v.z, v.w);
            *(uint4*)&Bs[r * 32 + ko8] = q;
        }
        __syncthreads();

        short8 a[4], bfr[4];
#pragma unroll
        for (int i = 0; i < 4; ++i)
            a[i] = *(const short8*)&As[(wm * 64 + i * 16 + ar) * 32 + ko];
#pragma unroll
        for (int jj = 0; jj < 4; ++jj)
            bfr[jj] = *(const short8*)&Bs[(wn * 64 + jj * 16 + ar) * 32 + ko];
#pragma unroll
        for (int i = 0; i < 4; ++i)
#pragma unroll
            for (int jj = 0; jj < 4; ++jj)
                acc[i][jj] = __builtin_amdgcn_mfma_f32_16x16x32_bf16(
                    a[i], bfr[jj], acc[i][jj], 0, 0, 0);
        __syncthreads();
    }

    int fr = lane & 15, fq = lane >> 4;
#pragma unroll
    for (int jj = 0; jj < 4; ++jj) {
        int col = n0 + wn * 64 + jj * 16 + fr;
        float bias = bih[col] + bhh[col];
#pragma unroll
        for (int i = 0; i < 4; ++i) {
            int row = m0 + wm * 64 + i * 16 + fq * 4;
#pragma unroll
            for (int q = 0; q < 4; ++q)
                xW[(size_t)(row + q) * H_DIM + col] = acc[i][jj][q] + bias;
        }
    }
}

// ---------------------------------------------------------------------------
// krnn: persistent recurrence. 32 blocks x 256 thr (4 waves), 1 launch.
// Block (bg = blk&1: 16 batches, ngg = blk>>1: 64 n-cols). Wave w owns
// n-tile ngg*64 + w*16. W_hh bf16 B-frags PINNED register-resident via
// loop-carried asm keep-alive (128 VGPR/wave; 1 wave/SIMD -> 512 budget).
// Per step: 32 A-frags of h_{t-1} from global, 32 MFMA, +xW, inline tanh,
// publish h_t write-through (4B agent-scope stores, col-pair packed).
// xW for step t+1 prefetched BEFORE the barrier wait. Barrier per step and
// per batch-group: distributed per-block monotonic flags; arrival = one
// RELEASE store (tid0); wait = lanes 0..15 poll one flag each; one ACQUIRE
// load; syncthreads.
// ---------------------------------------------------------------------------
__global__ __launch_bounds__(256, 1) void krnn(const uint16_t* __restrict__ hbInit,
                                               const uint16_t* __restrict__ Wb,
                                               const float* __restrict__ xW,
                                               uint16_t* __restrict__ Hb,
                                               uint32_t* __restrict__ flags) {
    int blk = blockIdx.x;
    int bg = blk & 1;
    int ngg = blk >> 1;
    int tid = threadIdx.x;
    int w = tid >> 6, lane = tid & 63;
    int ncol0 = ngg * 64 + w * 16;
    int lr = lane & 15, lk = (lane >> 4) * 8;

    // B-frags: lane holds Wb[ncol0+lr][kt*32 + lk + 0..7]
    short8 wf[32];
    const uint16_t* wrow = Wb + (size_t)(ncol0 + lr) * H_DIM + lk;
#pragma unroll
    for (int kt = 0; kt < 32; ++kt)
        wf[kt] = *(const short8*)(wrow + (size_t)kt * 32);

    int brow = bg * 16 + lr;              // A row (batch) this lane loads
    int eb = bg * 16 + (lane >> 4) * 4;   // epilogue batch base
    int en = ncol0 + lr;                  // epilogue out col
    uint32_t* Hb32 = (uint32_t*)Hb;
    uint32_t* myflag = flags + (size_t)(bg * 16 + ngg) * 32;  // 128B spacing
    const uint32_t* grpflags = flags + (size_t)(bg * 16) * 32;

    // prefetch xW for t=0
    float xv[4];
#pragma unroll
    for (int q = 0; q < 4; ++q)
        xv[q] = xW[((size_t)(eb + q) * T_SEQ + 0) * H_DIM + en];

    for (int t = 0; t < T_SEQ; ++t) {
        // pin W-frags: loop-carried register dependency, no refetch/spill
#pragma unroll
        for (int kt = 0; kt < 32; ++kt)
            asm volatile("" : "+v"(wf[kt]));

        const uint16_t* abase;
        size_t astride;
        if (t == 0) { abase = hbInit; astride = H_DIM; }
        else { abase = Hb + (size_t)(t - 1) * H_DIM; astride = (size_t)T_SEQ * H_DIM; }
        const uint16_t* arow = abase + (size_t)brow * astride + lk;

        v4f ac0 = {0.f,0.f,0.f,0.f}, ac1 = {0.f,0.f,0.f,0.f};
        v4f ac2 = {0.f,0.f,0.f,0.f}, ac3 = {0.f,0.f,0.f,0.f};
        short8 af[16];
#pragma unroll
        for (int kt = 0; kt < 16; ++kt)
            af[kt] = *(const short8*)(arow + (size_t)kt * 32);
#pragma unroll
        for (int kt = 0; kt < 16; ++kt) {
            v4f* a = (kt & 3) == 0 ? &ac0 : (kt & 3) == 1 ? &ac1 : (kt & 3) == 2 ? &ac2 : &ac3;
            *a = __builtin_amdgcn_mfma_f32_16x16x32_bf16(af[kt], wf[kt], *a, 0, 0, 0);
        }
#pragma unroll
        for (int kt = 0; kt < 16; ++kt)
            af[kt] = *(const short8*)(arow + 512 + (size_t)kt * 32);
#pragma unroll
        for (int kt = 0; kt < 16; ++kt) {
            v4f* a = (kt & 3) == 0 ? &ac0 : (kt & 3) == 1 ? &ac1 : (kt & 3) == 2 ? &ac2 : &ac3;
            *a = __builtin_amdgcn_mfma_f32_16x16x32_bf16(af[kt], wf[16 + kt], *a, 0, 0, 0);
        }
        v4f acc = (ac0 + ac1) + (ac2 + ac3);

        float hv[4];
#pragma unroll
        for (int q = 0; q < 4; ++q)
            hv[q] = fast_tanh(acc[q] + xv[q]);

        // publish write-through: pair lanes -> 4B words, 2 stores/lane
#pragma unroll
        for (int q = 0; q < 4; ++q) {
            float pv = __shfl_xor(hv[q], 1);
            bool mine = ((lane & 1) == 0) ? (q < 2) : (q >= 2);
            if (mine) {
                uint32_t word = (lane & 1) ? pack2(pv, hv[q]) : pack2(hv[q], pv);
                size_t i32 = (((size_t)(eb + q) * T_SEQ + t) * H_DIM + (size_t)(en & ~1)) >> 1;
                __hip_atomic_store(&Hb32[i32], word, __ATOMIC_RELAXED,
                                   __HIP_MEMORY_SCOPE_AGENT);
            }
        }

        if (t < T_SEQ - 1) {
            // prefetch next step's xW while the barrier settles
            float xn[4];
#pragma unroll
            for (int q = 0; q < 4; ++q)
                xn[q] = xW[((size_t)(eb + q) * T_SEQ + (t + 1)) * H_DIM + en];

            __syncthreads();   // drains each wave's stores before arrival
            if (tid == 0)
                __hip_atomic_store(myflag, (uint32_t)(t + 1), __ATOMIC_RELEASE,
                                   __HIP_MEMORY_SCOPE_AGENT);
            if (tid < 16) {
                const uint32_t* f = grpflags + (size_t)tid * 32;
                while (__hip_atomic_load(f, __ATOMIC_RELAXED,
                                         __HIP_MEMORY_SCOPE_AGENT) <= (uint32_t)t)
                    __builtin_amdgcn_s_sleep(2);
            }
            if (tid == 0)
                (void)__hip_atomic_load(myflag, __ATOMIC_ACQUIRE,
                                        __HIP_MEMORY_SCOPE_AGENT);  // L1+L2 inv
            __syncthreads();

#pragma unroll
            for (int q = 0; q < 4; ++q) xv[q] = xn[q];
        }
    }
}

// ---------------------------------------------------------------------------
// kgemm: out[m][gc0+n] = sum_k Hb[m][k] * WbChunk[n][k] + b_out[gc0+n]
// bf16 MFMA 16x16x32, 128x128 tile, BK=32, 4 waves, global_load_lds staging.
// Per chunk: 50 nt x 32 mt, bid = nt*32 + mt (A panel L3-reused).
// ---------------------------------------------------------------------------
__global__ __launch_bounds__(256) void kgemm(const uint16_t* __restrict__ Ab,
                                             const uint16_t* __restrict__ Bb,
                                             const float* __restrict__ bout,
                                             float* __restrict__ out,
                                             int gc0) {
    __shared__ __align__(16) uint16_t As[128 * 32];
    __shared__ __align__(16) uint16_t Bs[128 * 32];

    int bid = blockIdx.x;
    int nt = bid >> 5, mt = bid & 31;
    int m0 = mt * 128, n0 = nt * 128;
    int tid = threadIdx.x;
    int lane = tid & 63;

    v4f acc[4][4] = {};
    int wv = tid >> 6, wm = wv >> 1, wn = wv & 1;
    int ar = lane & 15, ko = (lane >> 4) * 8;

    for (int k0 = 0; k0 < H_DIM; k0 += 32) {
        int wb = tid & ~63;   // wave-uniform base (16B units)
#pragma unroll
        for (int l = 0; l < 2; ++l) {
            int c = tid + l * 256;
            int r = c >> 2, ko8 = (c & 3) * 8;
            gload16(&Ab[(size_t)(m0 + r) * H_DIM + k0 + ko8],
                    (char*)As + (size_t)(wb + l * 256) * 16);
            gload16(&Bb[(size_t)(n0 + r) * H_DIM + k0 + ko8],
                    (char*)Bs + (size_t)(wb + l * 256) * 16);
        }
        __syncthreads();

        short8 a[4], bfr[4];
#pragma unroll
        for (int i = 0; i < 4; ++i)
            a[i] = *(const short8*)&As[(wm * 64 + i * 16 + ar) * 32 + ko];
#pragma unroll
        for (int jj = 0; jj < 4; ++jj)
            bfr[jj] = *(const short8*)&Bs[(wn * 64 + jj * 16 + ar) * 32 + ko];
#pragma unroll
        for (int i = 0; i < 4; ++i)
#pragma unroll
            for (int jj = 0; jj < 4; ++jj)
                acc[i][jj] = __builtin_amdgcn_mfma_f32_16x16x32_bf16(
                    a[i], bfr[jj], acc[i][jj], 0, 0, 0);
        __syncthreads();
    }

    int fr = lane & 15, fq = lane >> 4;
#pragma unroll
    for (int jj = 0; jj < 4; ++jj) {
        int col = gc0 + n0 + wn * 64 + jj * 16 + fr;
        float bo = bout[col];
#pragma unroll
        for (int i = 0; i < 4; ++i) {
            int row = m0 + wm * 64 + i * 16 + fq * 4;
#pragma unroll
            for (int q = 0; q < 4; ++q)
                out[(size_t)(row + q) * V_DIM + col] = acc[i][jj][q] + bo;
        }
    }
}

// ---------------------------------------------------------------------------
extern "C" void kernel_launch(void* const* d_in, const int* in_sizes, int n_in,
                              void* d_out, int out_size, void* d_ws, size_t ws_size,
                              hipStream_t stream) {
    const int*   target = (const int*)d_in[0];
    const float* h0     = (const float*)d_in[1];
    const float* emb    = (const float*)d_in[2];
    const float* Wih    = (const float*)d_in[3];
    const float* bih    = (const float*)d_in[4];
    const float* Whh    = (const float*)d_in[5];
    const float* bhh    = (const float*)d_in[6];
    const float* Wout   = (const float*)d_in[7];
    const float* bout   = (const float*)d_in[8];
    float* out = (float*)d_out;

    char* ws = (char*)d_ws;
    // ws layout (bytes) — total 27,332,608:
    float*    xW     = (float*)(ws);                    // 16,777,216
    uint16_t* WbHH   = (uint16_t*)(ws + 16777216);      //  2,097,152
    uint16_t* hbInit = (uint16_t*)(ws + 18874368);      //     65,536
    uint32_t* flags  = (uint32_t*)(ws + 18939904);      //      4,096
    uint16_t* Hb     = (uint16_t*)(ws + 18944000);      //  8,388,608
    uint16_t* WbOut  = (uint16_t*)(ws);                 // 13,107,200 (reuses dead xW)

    kconv<<<512, 256, 0, stream>>>(Whh, WbHH);       // 1,048,576 elts
    kconv<<<16, 256, 0, stream>>>(h0, hbInit);       //    32,768 elts
    kxwm<<<dim3(32, 8), 256, 0, stream>>>(target, emb, Wih, bih, bhh, xW);
    hipMemsetAsync(flags, 0, 4096, stream);
    krnn<<<32, 256, 0, stream>>>(hbInit, WbHH, xW, Hb, flags);

    // decode GEMM in 5 column chunks of 6400 (WbOut lives in dead xW region)
    for (int c = 0; c < 5; ++c) {
        kconv<<<3200, 256, 0, stream>>>(Wout + (size_t)c * 6553600, WbOut);
        kgemm<<<1600, 256, 0, stream>>>(Hb, WbOut, bout, out, c * 6400);
    }
}

// Round 6
// 1181.153 us; speedup vs baseline: 1.2057x; 1.2057x over previous
//
#include <hip/hip_runtime.h>
#include <stdint.h>

#define T_SEQ 128
#define B_SZ  32
#define H_DIM 1024
#define E_DIM 512
#define V_DIM 32000
#define SOS_TOK 1
#define NCONS 448
#define NTILES 8000   // 32 mt' x 250 nt

typedef float v4f __attribute__((ext_vector_type(4)));
typedef short short8 __attribute__((ext_vector_type(8)));

// RNE float->bf16
__device__ inline uint16_t f2bf(float x) {
    uint32_t u = __float_as_uint(x);
    uint32_t r = (u + 0x7fffu + ((u >> 16) & 1u)) >> 16;
    return (uint16_t)r;
}
__device__ inline uint32_t pack2(float a, float b) {
    return (uint32_t)f2bf(a) | ((uint32_t)f2bf(b) << 16);
}

// async global->LDS, 16B per lane. lds base must be wave-uniform.
__device__ inline void gload16(const void* g, void* l) {
    __builtin_amdgcn_global_load_lds(
        (const __attribute__((address_space(1))) uint32_t*)g,
        (__attribute__((address_space(3))) uint32_t*)l, 16, 0, 0);
}

// ---------------------------------------------------------------------------
// kconv: fp32 -> bf16, 2048 elements per block
// ---------------------------------------------------------------------------
__global__ __launch_bounds__(256) void kconv(const float* __restrict__ W,
                                             uint16_t* __restrict__ Wb) {
    size_t i = ((size_t)blockIdx.x * 256 + threadIdx.x) * 8;
    float4 a = *(const float4*)&W[i];
    float4 c = *(const float4*)&W[i + 4];
    uint4 p;
    p.x = pack2(a.x, a.y); p.y = pack2(a.z, a.w);
    p.z = pack2(c.x, c.y); p.w = pack2(c.z, c.w);
    *(uint4*)&Wb[i] = p;
}

// ---------------------------------------------------------------------------
// kxwm: xW[t*B+b][n] = emb[tok(b,t)] . Wih[n] + bih[n] + bhh[n]   (bf16 MFMA)
// M=4096, N=1024, K=512. 128x128 tile, BK=32, 4 waves, reg-staged fp32->bf16.
// GEMM row index m = b*T+t (token gather); OUTPUT written at [t*B+b].
// ---------------------------------------------------------------------------
__global__ __launch_bounds__(256) void kxwm(const int* __restrict__ target,
                                            const float* __restrict__ emb,
                                            const float* __restrict__ Wih,
                                            const float* __restrict__ bih,
                                            const float* __restrict__ bhh,
                                            float* __restrict__ xW) {
    __shared__ __align__(16) uint16_t As[128 * 32];
    __shared__ __align__(16) uint16_t Bs[128 * 32];
    __shared__ int toks[128];
    int m0 = blockIdx.x * 128, n0 = blockIdx.y * 128;
    int tid = threadIdx.x;
    if (tid < 128) {
        int row = m0 + tid;
        int t = row & (T_SEQ - 1);
        toks[tid] = (t == 0) ? SOS_TOK : target[row];
    }
    __syncthreads();

    v4f acc[4][4] = {};
    int lane = tid & 63, wv = tid >> 6, wm = wv >> 1, wn = wv & 1;
    int ar = lane & 15, ko = (lane >> 4) * 8;

    for (int k0 = 0; k0 < E_DIM; k0 += 32) {
#pragma unroll
        for (int l = 0; l < 2; ++l) {
            int c = tid + l * 256;
            int r = c >> 2, ko8 = (c & 3) * 8;
            const float* asrc = &emb[(size_t)toks[r] * E_DIM + k0 + ko8];
            float4 x = *(const float4*)asrc;
            float4 y = *(const float4*)(asrc + 4);
            uint4 p;
            p.x = pack2(x.x, x.y); p.y = pack2(x.z, x.w);
            p.z = pack2(y.x, y.y); p.w = pack2(y.z, y.w);
            *(uint4*)&As[r * 32 + ko8] = p;
            const float* bsrc = &Wih[(size_t)(n0 + r) * E_DIM + k0 + ko8];
            float4 u = *(const float4*)bsrc;
            float4 v = *(const float4*)(bsrc + 4);
            uint4 q;
            q.x = pack2(u.x, u.y); q.y = pack2(u.z, u.w);
            q.z = pack2(v.x, v.y); q.w = pack2(v.z, v.w);
            *(uint4*)&Bs[r * 32 + ko8] = q;
        }
        __syncthreads();

        short8 a[4], bfr[4];
#pragma unroll
        for (int i = 0; i < 4; ++i)
            a[i] = *(const short8*)&As[(wm * 64 + i * 16 + ar) * 32 + ko];
#pragma unroll
        for (int jj = 0; jj < 4; ++jj)
            bfr[jj] = *(const short8*)&Bs[(wn * 64 + jj * 16 + ar) * 32 + ko];
#pragma unroll
        for (int i = 0; i < 4; ++i)
#pragma unroll
            for (int jj = 0; jj < 4; ++jj)
                acc[i][jj] = __builtin_amdgcn_mfma_f32_16x16x32_bf16(
                    a[i], bfr[jj], acc[i][jj], 0, 0, 0);
        __syncthreads();
    }

    int fr = lane & 15, fq = lane >> 4;
#pragma unroll
    for (int jj = 0; jj < 4; ++jj) {
        int col = n0 + wn * 64 + jj * 16 + fr;
        float bias = bih[col] + bhh[col];
#pragma unroll
        for (int i = 0; i < 4; ++i) {
            int row = m0 + wm * 64 + i * 16 + fq * 4;
#pragma unroll
            for (int q = 0; q < 4; ++q) {
                int m = row + q;                 // = b*T + t
                int b = m >> 7, t = m & (T_SEQ - 1);
                xW[((size_t)t * B_SZ + b) * H_DIM + col] = acc[i][jj][q] + bias;
            }
        }
    }
}

// ---------------------------------------------------------------------------
// kfused: 480 blocks x 256 thr.
//  blocks 0..31   : recurrence producers (R4-proven krnn structure; Hb/xW in
//                   [t][b][H] layout; per-step distributed-flag barrier;
//                   flag t+1 released EVERY step incl. t=127).
//  blocks 32..479 : decode consumers. Tile g = c, c+448, ... ;
//                   (mt', nt) = (g/250, g%250); gate: all 32 flags >= 4mt'+4.
//                   128x128 bf16-MFMA tile, A = Hb (global_load_lds),
//                   B = W_out fp32 reg-packed to bf16. Epilogue remaps row
//                   m' = t*B+b -> out[(b*T+t)*V + col].
// Grid 480 <= full-residency capacity (>=3 blk/CU at ~112 VGPR, 16KB LDS)
// -> producers always resident -> no gate deadlock.
// ---------------------------------------------------------------------------
__global__ __launch_bounds__(256) void kfused(const uint16_t* __restrict__ hbInit,
                                              const uint16_t* __restrict__ WbHH,
                                              const float* __restrict__ xW,
                                              uint16_t* __restrict__ Hb,
                                              uint32_t* __restrict__ flags,
                                              const float* __restrict__ Wout,
                                              const float* __restrict__ bout,
                                              float* __restrict__ out) {
    __shared__ __align__(16) uint16_t As[128 * 32];
    __shared__ __align__(16) uint16_t Bs[128 * 32];
    int tid = threadIdx.x;
    int lane = tid & 63;

    if (blockIdx.x < 32) {
        // ---------------- producer: recurrence ----------------
        __builtin_amdgcn_s_setprio(1);
        int blk = blockIdx.x;
        int bg = blk & 1, ngg = blk >> 1;
        int w = tid >> 6;
        int ncol0 = ngg * 64 + w * 16;
        int lr = lane & 15, lk = (lane >> 4) * 8;

        short8 wf[32];
        const uint16_t* wrow = WbHH + (size_t)(ncol0 + lr) * H_DIM + lk;
#pragma unroll
        for (int kt = 0; kt < 32; ++kt)
            wf[kt] = *(const short8*)(wrow + (size_t)kt * 32);

        int brow = bg * 16 + lr;
        int eb = bg * 16 + (lane >> 4) * 4;
        int en = ncol0 + lr;
        uint32_t* Hb32 = (uint32_t*)Hb;
        uint32_t* myflag = flags + (size_t)(bg * 16 + ngg) * 32;
        const uint32_t* grpflags = flags + (size_t)(bg * 16) * 32;

        for (int t = 0; t < T_SEQ; ++t) {
            const uint16_t* arow =
                ((t == 0) ? hbInit : Hb + (size_t)(t - 1) * B_SZ * H_DIM)
                + (size_t)brow * H_DIM + lk;

            float xv[4];
#pragma unroll
            for (int q = 0; q < 4; ++q)
                xv[q] = xW[((size_t)t * B_SZ + eb + q) * H_DIM + en];

            v4f ac0 = {0.f,0.f,0.f,0.f}, ac1 = {0.f,0.f,0.f,0.f};
            v4f ac2 = {0.f,0.f,0.f,0.f}, ac3 = {0.f,0.f,0.f,0.f};
            short8 af[16];
#pragma unroll
            for (int kt = 0; kt < 16; ++kt)
                af[kt] = *(const short8*)(arow + (size_t)kt * 32);
#pragma unroll
            for (int kt = 0; kt < 16; ++kt) {
                v4f* a = (kt & 3) == 0 ? &ac0 : (kt & 3) == 1 ? &ac1
                        : (kt & 3) == 2 ? &ac2 : &ac3;
                *a = __builtin_amdgcn_mfma_f32_16x16x32_bf16(af[kt], wf[kt], *a, 0, 0, 0);
            }
#pragma unroll
            for (int kt = 0; kt < 16; ++kt)
                af[kt] = *(const short8*)(arow + 512 + (size_t)kt * 32);
#pragma unroll
            for (int kt = 0; kt < 16; ++kt) {
                v4f* a = (kt & 3) == 0 ? &ac0 : (kt & 3) == 1 ? &ac1
                        : (kt & 3) == 2 ? &ac2 : &ac3;
                *a = __builtin_amdgcn_mfma_f32_16x16x32_bf16(af[kt], wf[16 + kt], *a, 0, 0, 0);
            }
            v4f acc = (ac0 + ac1) + (ac2 + ac3);

            float hv[4];
#pragma unroll
            for (int q = 0; q < 4; ++q)
                hv[q] = tanhf(acc[q] + xv[q]);

            // publish write-through: pair lanes -> 4B words, 2 stores/lane
#pragma unroll
            for (int q = 0; q < 4; ++q) {
                float pv = __shfl_xor(hv[q], 1);
                bool mine = ((lane & 1) == 0) ? (q < 2) : (q >= 2);
                if (mine) {
                    uint32_t word = (lane & 1) ? pack2(pv, hv[q]) : pack2(hv[q], pv);
                    size_t i32 = (((size_t)t * B_SZ + eb + q) * H_DIM
                                  + (size_t)(en & ~1)) >> 1;
                    __hip_atomic_store(&Hb32[i32], word, __ATOMIC_RELAXED,
                                       __HIP_MEMORY_SCOPE_AGENT);
                }
            }

            __syncthreads();   // drain all waves' stores before arrival
            if (tid == 0)
                __hip_atomic_store(myflag, (uint32_t)(t + 1), __ATOMIC_RELEASE,
                                   __HIP_MEMORY_SCOPE_AGENT);
            if (t < T_SEQ - 1) {
                if (tid < 16) {
                    const uint32_t* f = grpflags + (size_t)tid * 32;
                    while (__hip_atomic_load(f, __ATOMIC_RELAXED,
                                             __HIP_MEMORY_SCOPE_AGENT) <= (uint32_t)t)
                        __builtin_amdgcn_s_sleep(2);
                }
                if (tid == 0)
                    (void)__hip_atomic_load(myflag, __ATOMIC_ACQUIRE,
                                            __HIP_MEMORY_SCOPE_AGENT);
                __syncthreads();
            }
        }
    } else {
        // ---------------- consumer: decode GEMM ----------------
        int c = blockIdx.x - 32;
        int wv = tid >> 6, wm = wv >> 1, wn = wv & 1;
        int ar = lane & 15, ko = (lane >> 4) * 8;
        int fr = lane & 15, fq = lane >> 4;
        int gate_seen = 0;

        for (int g = c; g < NTILES; g += NCONS) {
            int mtp = g / 250, nt = g - mtp * 250;
            int need = 4 * mtp + 4;
            if (need > gate_seen) {
                if (tid < 32) {
                    const uint32_t* f = flags + (size_t)tid * 32;
                    while (__hip_atomic_load(f, __ATOMIC_RELAXED,
                                             __HIP_MEMORY_SCOPE_AGENT) < (uint32_t)need)
                        __builtin_amdgcn_s_sleep(8);
                }
                __syncthreads();
                if (tid == 0)
                    (void)__hip_atomic_load(flags, __ATOMIC_ACQUIRE,
                                            __HIP_MEMORY_SCOPE_AGENT);
                __syncthreads();
                gate_seen = need;
            }

            int m0 = mtp * 128, n0 = nt * 128;
            v4f acc[4][4] = {};

            for (int k0 = 0; k0 < H_DIM; k0 += 32) {
                int wb = tid & ~63;
#pragma unroll
                for (int l = 0; l < 2; ++l) {
                    int cc = tid + l * 256;
                    int r = cc >> 2, ko8 = (cc & 3) * 8;
                    gload16(&Hb[(size_t)(m0 + r) * H_DIM + k0 + ko8],
                            (char*)As + (size_t)(wb + l * 256) * 16);
                    const float* src = &Wout[(size_t)(n0 + r) * H_DIM + k0 + ko8];
                    float4 x = *(const float4*)src;
                    float4 y = *(const float4*)(src + 4);
                    uint4 p;
                    p.x = pack2(x.x, x.y); p.y = pack2(x.z, x.w);
                    p.z = pack2(y.x, y.y); p.w = pack2(y.z, y.w);
                    *(uint4*)&Bs[r * 32 + ko8] = p;
                }
                __syncthreads();

                short8 a[4], bfr[4];
#pragma unroll
                for (int i = 0; i < 4; ++i)
                    a[i] = *(const short8*)&As[(wm * 64 + i * 16 + ar) * 32 + ko];
#pragma unroll
                for (int jj = 0; jj < 4; ++jj)
                    bfr[jj] = *(const short8*)&Bs[(wn * 64 + jj * 16 + ar) * 32 + ko];
#pragma unroll
                for (int i = 0; i < 4; ++i)
#pragma unroll
                    for (int jj = 0; jj < 4; ++jj)
                        acc[i][jj] = __builtin_amdgcn_mfma_f32_16x16x32_bf16(
                            a[i], bfr[jj], acc[i][jj], 0, 0, 0);
                __syncthreads();
            }

#pragma unroll
            for (int jj = 0; jj < 4; ++jj) {
                int col = n0 + wn * 64 + jj * 16 + fr;
                float bo = bout[col];
#pragma unroll
                for (int i = 0; i < 4; ++i) {
                    int rbase = wm * 64 + i * 16 + fq * 4;
#pragma unroll
                    for (int q = 0; q < 4; ++q) {
                        int mp = m0 + rbase + q;          // row in [t][b] space
                        int tt = mp >> 5, bb = mp & 31;
                        out[((size_t)bb * T_SEQ + tt) * V_DIM + col] =
                            acc[i][jj][q] + bo;
                    }
                }
            }
        }
    }
}

// ---------------------------------------------------------------------------
extern "C" void kernel_launch(void* const* d_in, const int* in_sizes, int n_in,
                              void* d_out, int out_size, void* d_ws, size_t ws_size,
                              hipStream_t stream) {
    const int*   target = (const int*)d_in[0];
    const float* h0     = (const float*)d_in[1];
    const float* emb    = (const float*)d_in[2];
    const float* Wih    = (const float*)d_in[3];
    const float* bih    = (const float*)d_in[4];
    const float* Whh    = (const float*)d_in[5];
    const float* bhh    = (const float*)d_in[6];
    const float* Wout   = (const float*)d_in[7];
    const float* bout   = (const float*)d_in[8];
    float* out = (float*)d_out;

    char* ws = (char*)d_ws;
    // ws layout (bytes) — total 27,332,608:
    float*    xW     = (float*)(ws);                    // 16,777,216
    uint16_t* WbHH   = (uint16_t*)(ws + 16777216);      //  2,097,152
    uint16_t* hbInit = (uint16_t*)(ws + 18874368);      //     65,536
    uint32_t* flags  = (uint32_t*)(ws + 18939904);      //      4,096
    uint16_t* Hb     = (uint16_t*)(ws + 18944000);      //  8,388,608

    kconv<<<512, 256, 0, stream>>>(Whh, WbHH);       // 1,048,576 elts
    kconv<<<16, 256, 0, stream>>>(h0, hbInit);       //    32,768 elts
    kxwm<<<dim3(32, 8), 256, 0, stream>>>(target, emb, Wih, bih, bhh, xW);
    hipMemsetAsync(flags, 0, 4096, stream);
    kfused<<<32 + NCONS, 256, 0, stream>>>(hbInit, WbHH, xW, Hb, flags,
                                           Wout, bout, out);
}